// Round 9
// baseline (517.887 us; speedup 1.0000x reference)
//
#include <hip/hip_runtime.h>
#include <hip/hip_bf16.h>
#include <cstdint>
#include <cstddef>

#define C_CLS   100000
#define D_FEAT  512
#define B_ROWS  512
#define NBN     782          /* ceil(100000/128) */
#define NBLK    (4 * NBN)    /* 3128 gemm blocks */

#define COSM 0.8775825618903728f
#define SINM 0.479425538604203f
#define TH_  (-0.8775825618903728f)
#define MM_  0.2397127693021015f   /* sin(0.5)*0.5 */

typedef __bf16 bf16x8 __attribute__((ext_vector_type(8)));
typedef float  f32x4  __attribute__((ext_vector_type(4)));

// ---------------- kernel 1: normalize ALL rows (w then x) -> bf16 ---------
// blocks 0..24999 handle w rows (4/block); blocks 25000..25127 handle x rows.
// Block 25000 additionally zeroes row_sum[512] and the ticket counter.
__global__ void k_norm(const float* __restrict__ x, const float* __restrict__ w,
                       __bf16* __restrict__ xn, __bf16* __restrict__ wn,
                       float* __restrict__ row_sum, int* __restrict__ counter) {
    const int r4   = blockIdx.x * 4 + (threadIdx.x >> 6);
    const int lane = threadIdx.x & 63;
    const float* src;
    __bf16*      dst;
    if (r4 < C_CLS) {
        src = w  + (size_t)r4 * D_FEAT;
        dst = wn + (size_t)r4 * D_FEAT;
    } else {
        src = x  + (size_t)(r4 - C_CLS) * D_FEAT;
        dst = xn + (size_t)(r4 - C_CLS) * D_FEAT;
    }
    const f32x4* p = (const f32x4*)src;
    f32x4 a = p[lane * 2];
    f32x4 b = p[lane * 2 + 1];
    float s = a[0]*a[0] + a[1]*a[1] + a[2]*a[2] + a[3]*a[3]
            + b[0]*b[0] + b[1]*b[1] + b[2]*b[2] + b[3]*b[3];
    #pragma unroll
    for (int m = 32; m >= 1; m >>= 1) s += __shfl_xor(s, m, 64);
    const float inv = 1.0f / fmaxf(sqrtf(s), 1e-12f);
    bf16x8 o;
    o[0] = (__bf16)(a[0]*inv); o[1] = (__bf16)(a[1]*inv);
    o[2] = (__bf16)(a[2]*inv); o[3] = (__bf16)(a[3]*inv);
    o[4] = (__bf16)(b[0]*inv); o[5] = (__bf16)(b[1]*inv);
    o[6] = (__bf16)(b[2]*inv); o[7] = (__bf16)(b[3]*inv);
    *(bf16x8*)(dst + lane * 8) = o;

    if (blockIdx.x == C_CLS / 4) {          // block 25000 (an x-block)
        row_sum[threadIdx.x]       = 0.0f;
        row_sum[threadIdx.x + 256] = 0.0f;
        if (threadIdx.x == 0) *counter = 0;
    }
}

// ---------------- kernel 2: register-direct MFMA GEMM (no LDS staging) ----
// Fragment loads go straight from global (L1/L2-backed) to VGPRs:
// one wave's bf16x8 fragment load = 64 lanes covering 16 fully-consumed
// 64B cachelines (ideal 1KB/instruction). No barriers, no async copies,
// no waitcnt asm -- the compiler software-pipelines loads across kt freely.
// All per-kt addresses fold to 8 hoisted bases + 13-bit immediates.
// Epilogue + ticket finalization identical to verified round 7.
__global__ __launch_bounds__(256, 2) void k_gemm(
        const __bf16* __restrict__ xn, const __bf16* __restrict__ wn,
        const int* __restrict__ y,
        float* __restrict__ row_sum, float* __restrict__ tlogit,
        int* __restrict__ counter, float* __restrict__ out) {

    __shared__ int   ys[128];
    __shared__ float red[2][128];
    __shared__ int   lastflag;
    __shared__ float pr[4];

    const int tid = threadIdx.x;
    // XCD-aware swizzle: 3128 = 8*391 exact, XCD x gets [x*391, (x+1)*391)
    const int wg = (blockIdx.x & 7) * (NBLK / 8) + (blockIdx.x >> 3);
    const int bm = wg & 3;
    const int bn = wg >> 2;

    if (tid < 128) ys[tid] = y[bm * 128 + tid];

    const int wave = tid >> 6;
    const int lane = tid & 63;
    const int wm   = wave >> 1;     // 0..1
    const int wn_  = wave & 1;      // 0..1
    const int quad = lane >> 4;     // 0..3
    const int l15  = lane & 15;

    // hoisted fragment base pointers (16B aligned); kt offsets are imm-foldable
    const __bf16* aB[4];
    #pragma unroll
    for (int mi = 0; mi < 4; ++mi)
        aB[mi] = xn + (size_t)(bm * 128 + wm * 64 + mi * 16 + l15) * D_FEAT + quad * 8;
    const __bf16* bB[4];
    #pragma unroll
    for (int ni = 0; ni < 4; ++ni) {
        int grow = bn * 128 + wn_ * 64 + ni * 16 + l15;
        if (grow > C_CLS - 1) grow = C_CLS - 1;
        bB[ni] = wn + (size_t)grow * D_FEAT + quad * 8;
    }

    f32x4 acc[4][4];
    #pragma unroll
    for (int i = 0; i < 4; ++i)
        #pragma unroll
        for (int j = 0; j < 4; ++j) acc[i][j] = (f32x4){0.f, 0.f, 0.f, 0.f};

    #pragma unroll 4
    for (int kt = 0; kt < 16; ++kt) {
        bf16x8 af[4], bfr[4];
        #pragma unroll
        for (int mi = 0; mi < 4; ++mi)
            af[mi] = *(const bf16x8*)(aB[mi] + kt * 32);
        #pragma unroll
        for (int ni = 0; ni < 4; ++ni)
            bfr[ni] = *(const bf16x8*)(bB[ni] + kt * 32);
        #pragma unroll
        for (int mi = 0; mi < 4; ++mi)
            #pragma unroll
            for (int ni = 0; ni < 4; ++ni)
                acc[mi][ni] = __builtin_amdgcn_mfma_f32_16x16x32_bf16(af[mi], bfr[ni], acc[mi][ni], 0, 0, 0);
    }

    __syncthreads();   // ys visibility (k-loop has no barriers anymore)

    // ---- epilogue: cos -> margin -> exp(logit-64) -> per-row partials ----
    #pragma unroll
    for (int mi = 0; mi < 4; ++mi) {
        float rs[4] = {0.f, 0.f, 0.f, 0.f};
        #pragma unroll
        for (int ni = 0; ni < 4; ++ni) {
            const int gcol = bn * 128 + wn_ * 64 + ni * 16 + l15;
            const bool colv = (gcol < C_CLS);
            #pragma unroll
            for (int reg = 0; reg < 4; ++reg) {
                const int lrow = wm * 64 + mi * 16 + quad * 4 + reg;
                const float cosv = acc[mi][ni][reg];
                const float sinv = sqrtf(fmaxf(1.0f - cosv * cosv, 0.0f));
                const float phi  = (cosv > TH_) ? (cosv * COSM - sinv * SINM) : (cosv - MM_);
                const bool ist   = colv && (gcol == ys[lrow]);
                const float logit = 64.0f * (ist ? phi : cosv);
                if (ist) atomicExch(&tlogit[bm * 128 + lrow], logit);
                rs[reg] += colv ? __expf(logit - 64.0f) : 0.0f;
            }
        }
        #pragma unroll
        for (int reg = 0; reg < 4; ++reg) {
            float v = rs[reg];
            v += __shfl_xor(v, 8, 64);
            v += __shfl_xor(v, 4, 64);
            v += __shfl_xor(v, 2, 64);
            v += __shfl_xor(v, 1, 64);
            if (l15 == 0) red[wn_][wm * 64 + mi * 16 + quad * 4 + reg] = v;
        }
    }
    __syncthreads();
    if (tid < 128) {
        const float v = red[0][tid] + red[1][tid];
        atomicAdd(&row_sum[bm * 128 + tid], v);
    }

    // ---- ticket: last block finalizes the loss ---------------------------
    __syncthreads();
    if (tid == 0) {
        const int t = atomicAdd(counter, 1);
        lastflag = (t == NBLK - 1) ? 1 : 0;
    }
    __syncthreads();
    if (lastflag) {
        float part = 0.0f;
        #pragma unroll
        for (int i = 0; i < 2; ++i) {
            const int row = tid + i * 256;
            const float rsv = atomicAdd(&row_sum[row], 0.0f);   // coherent read
            const float tlv = atomicAdd(&tlogit[row], 0.0f);    // coherent read
            part += logf(rsv) + 64.0f - tlv;
        }
        #pragma unroll
        for (int m = 32; m >= 1; m >>= 1) part += __shfl_xor(part, m, 64);
        if ((tid & 63) == 0) pr[tid >> 6] = part;
        __syncthreads();
        if (tid == 0)
            out[0] = (pr[0] + pr[1] + pr[2] + pr[3]) * (1.0f / 512.0f);
    }
}

extern "C" void kernel_launch(void* const* d_in, const int* in_sizes, int n_in,
                              void* d_out, int out_size, void* d_ws, size_t ws_size,
                              hipStream_t stream) {
    const float* x = (const float*)d_in[0];
    const int*   y = (const int*)d_in[1];
    const float* w = (const float*)d_in[2];

    char* ws = (char*)d_ws;
    __bf16* xn      = (__bf16*)ws;                                // 524288 B
    __bf16* wn      = (__bf16*)(ws + 524288);                     // 102400000 B
    float*  row_sum = (float*)(ws + 524288 + 102400000);          // 2048 B
    float*  tlogit  = (float*)(ws + 524288 + 102400000 + 2048);   // 2048 B
    int*    counter = (int*)(ws + 524288 + 102400000 + 4096);     // 4 B
    float*  out     = (float*)d_out;

    hipLaunchKernelGGL(k_norm, dim3((C_CLS + B_ROWS) / 4), dim3(256), 0, stream,
                       x, w, xn, wn, row_sum, counter);
    hipLaunchKernelGGL(k_gemm, dim3(NBLK), dim3(256), 0, stream,
                       xn, wn, y, row_sum, tlogit, counter, out);
}

// Round 10
// 428.208 us; speedup vs baseline: 1.2094x; 1.2094x over previous
//
#include <hip/hip_runtime.h>
#include <hip/hip_bf16.h>
#include <cstdint>
#include <cstddef>

#define C_CLS   100000
#define D_FEAT  512
#define B_ROWS  512
#define NBN     782          /* ceil(100000/128) */
#define NBLK    (4 * NBN)    /* 3128 gemm blocks */

#define COSM 0.8775825618903728f
#define SINM 0.479425538604203f
#define TH_  (-0.8775825618903728f)
#define MM_  0.2397127693021015f   /* sin(0.5)*0.5 */

typedef __bf16 bf16x8 __attribute__((ext_vector_type(8)));
typedef __bf16 bf16x4 __attribute__((ext_vector_type(4)));
typedef float  f32x4  __attribute__((ext_vector_type(4)));

typedef __attribute__((address_space(3))) void lds_void;
typedef const __attribute__((address_space(1))) void g_void;

__device__ __forceinline__ void async_copy16(const void* g, void* l) {
    __builtin_amdgcn_global_load_lds((g_void*)g, (lds_void*)l, 16, 0, 0);
}

// ---------------- kernel 1: normalize x rows -> bf16; zero accumulators ---
__global__ void k_xnorm(const float* __restrict__ x, __bf16* __restrict__ xn,
                        float* __restrict__ row_sum, int* __restrict__ counter) {
    const int row  = blockIdx.x * 4 + (threadIdx.x >> 6);   // 128 blocks x 4 rows
    const int lane = threadIdx.x & 63;
    const f32x4* p = (const f32x4*)(x + (size_t)row * D_FEAT);
    f32x4 a = p[lane * 2];
    f32x4 b = p[lane * 2 + 1];
    float s = a[0]*a[0] + a[1]*a[1] + a[2]*a[2] + a[3]*a[3]
            + b[0]*b[0] + b[1]*b[1] + b[2]*b[2] + b[3]*b[3];
    #pragma unroll
    for (int m = 32; m >= 1; m >>= 1) s += __shfl_xor(s, m, 64);
    const float inv = 1.0f / fmaxf(sqrtf(s), 1e-12f);
    bf16x8 o;
    o[0] = (__bf16)(a[0]*inv); o[1] = (__bf16)(a[1]*inv);
    o[2] = (__bf16)(a[2]*inv); o[3] = (__bf16)(a[3]*inv);
    o[4] = (__bf16)(b[0]*inv); o[5] = (__bf16)(b[1]*inv);
    o[6] = (__bf16)(b[2]*inv); o[7] = (__bf16)(b[3]*inv);
    *(bf16x8*)(xn + (size_t)row * D_FEAT + lane * 8) = o;

    if (blockIdx.x == 0) {
        row_sum[threadIdx.x]       = 0.0f;
        row_sum[threadIdx.x + 256] = 0.0f;
        if (threadIdx.x == 0) *counter = 0;
    }
}

// ---------------- kernel 2: single-pass GEMM over RAW fp32 weights --------
// Round-7's verified skeleton (2 buffers, counted vmcnt, two barriers per
// k-step, 128x128, 3 blocks/CU) with the weight-normalization folded in:
//  - B staged as fp32 (16 KB/tile) in a [quad][half][row][4xf32] plane
//    layout: fragment reads are 16 consecutive 16B slots per 16-lane group
//    -> 8 word-accesses/bank = HW minimum, no conflicts (round-1's 6.4M
//    4-way conflicts came from its interleaved 32B-row layout)
//  - row sum-of-squares accumulated inline from the fp32 values already in
//    registers during the bf16 fragment conversion (round-1-verified math)
//  - eliminates the 307 MB wn HBM round-trip and the heavy k_norm pass
__global__ __launch_bounds__(256, 3) void k_gemm(
        const __bf16* __restrict__ xn, const float* __restrict__ w,
        const int* __restrict__ y,
        float* __restrict__ row_sum, float* __restrict__ tlogit,
        int* __restrict__ counter, float* __restrict__ out) {

    __shared__ __align__(16) __bf16 As[2][4096];   // [buf][(quad*128+row)*8]      : 16 KB
    __shared__ __align__(16) float  Bs[2][4096];   // [buf][((q*2+h)*128+row)*4]   : 32 KB
    __shared__ int   ys[128];
    __shared__ float red[2][128];
    __shared__ int   lastflag;
    __shared__ float pr[4];

    const int tid = threadIdx.x;
    // XCD-aware swizzle: 3128 = 8*391 exact, XCD x gets [x*391, (x+1)*391)
    const int wg = (blockIdx.x & 7) * (NBLK / 8) + (blockIdx.x >> 3);
    const int bm = wg & 3;
    const int bn = wg >> 2;

    if (tid < 128) ys[tid] = y[bm * 128 + tid];

    const int wave = tid >> 6;
    const int lane = tid & 63;
    const int wm   = wave >> 1;     // 0..1
    const int wn_  = wave & 1;      // 0..1
    const int quad = lane >> 4;     // 0..3
    const int l15  = lane & 15;

    f32x4 acc[4][4];
    #pragma unroll
    for (int i = 0; i < 4; ++i)
        #pragma unroll
        for (int j = 0; j < 4; ++j) acc[i][j] = (f32x4){0.f, 0.f, 0.f, 0.f};
    float ssq[4] = {0.f, 0.f, 0.f, 0.f};

    // stage tile kt_ into buffer s. 6 global_load_lds / thread / tile.
    // A (bf16): 512 chunks, c -> quad=c>>7, row=c&127.
    // B (fp32): 1024 chunks, c -> quad=c>>8, half=(c>>7)&1, row=c&127;
    //           LDS linear in c (plane layout), global src offset q*8+h*4.
    #define STAGE(s, kt_) do {                                                          \
        const int k0_ = (kt_) * 32;                                                     \
        _Pragma("unroll")                                                               \
        for (int i_ = 0; i_ < 2; ++i_) {                                                \
            const int c_ = tid + i_ * 256;                                              \
            const int qc_ = c_ >> 7, rc_ = c_ & 127;                                    \
            async_copy16(xn + (size_t)(bm * 128 + rc_) * D_FEAT + k0_ + qc_ * 8,        \
                         &As[s][c_ * 8]);                                               \
        }                                                                               \
        _Pragma("unroll")                                                               \
        for (int i_ = 0; i_ < 4; ++i_) {                                                \
            const int c_ = tid + i_ * 256;                                              \
            const int qc_ = c_ >> 8, hc_ = (c_ >> 7) & 1, rc_ = c_ & 127;               \
            int grow_ = bn * 128 + rc_; if (grow_ > C_CLS - 1) grow_ = C_CLS - 1;       \
            async_copy16(w + (size_t)grow_ * D_FEAT + k0_ + qc_ * 8 + hc_ * 4,          \
                         &Bs[s][c_ * 4]);                                               \
        }                                                                               \
    } while (0)

    STAGE(0, 0);
    STAGE(1, 1);

    #pragma unroll
    for (int kt = 0; kt < 16; ++kt) {
        const int cur = kt & 1;

        // tile kt's 6 loads done; tile kt+1's 6 stay in flight
        if (kt < 15) asm volatile("s_waitcnt vmcnt(6)" ::: "memory");
        else         asm volatile("s_waitcnt vmcnt(0)" ::: "memory");
        __builtin_amdgcn_s_barrier();

        bf16x8 af[4];
        #pragma unroll
        for (int mi = 0; mi < 4; ++mi)
            af[mi] = *(const bf16x8*)&As[cur][(quad * 128 + wm * 64 + mi * 16 + l15) * 8];

        bf16x8 bfr[4];
        #pragma unroll
        for (int ni = 0; ni < 4; ++ni) {
            const int r = wn_ * 64 + ni * 16 + l15;
            f32x4 b0 = *(const f32x4*)&Bs[cur][((quad * 2 + 0) * 128 + r) * 4];
            f32x4 b1 = *(const f32x4*)&Bs[cur][((quad * 2 + 1) * 128 + r) * 4];
            ssq[ni] += b0[0]*b0[0] + b0[1]*b0[1] + b0[2]*b0[2] + b0[3]*b0[3]
                     + b1[0]*b1[0] + b1[1]*b1[1] + b1[2]*b1[2] + b1[3]*b1[3];
            bf16x8 t;
            t[0] = (__bf16)b0[0]; t[1] = (__bf16)b0[1]; t[2] = (__bf16)b0[2]; t[3] = (__bf16)b0[3];
            t[4] = (__bf16)b1[0]; t[5] = (__bf16)b1[1]; t[6] = (__bf16)b1[2]; t[7] = (__bf16)b1[3];
            bfr[ni] = t;
        }

        // all reads of buf[cur] retired -> safe to restage it
        asm volatile("s_waitcnt lgkmcnt(0)" ::: "memory");
        __builtin_amdgcn_s_barrier();
        if (kt < 14) STAGE(cur, kt + 2);

        #pragma unroll
        for (int mi = 0; mi < 4; ++mi)
            #pragma unroll
            for (int ni = 0; ni < 4; ++ni)
                acc[mi][ni] = __builtin_amdgcn_mfma_f32_16x16x32_bf16(af[mi], bfr[ni], acc[mi][ni], 0, 0, 0);
    }
    #undef STAGE

    // ---- finish weight norms: reduce ssq across the 4 quads --------------
    float invw[4];
    #pragma unroll
    for (int ni = 0; ni < 4; ++ni) {
        float s = ssq[ni];
        s += __shfl_xor(s, 16, 64);
        s += __shfl_xor(s, 32, 64);
        invw[ni] = 1.0f / fmaxf(sqrtf(s), 1e-12f);
    }

    // ---- epilogue: cos -> margin -> exp(logit-64) -> per-row partials ----
    #pragma unroll
    for (int mi = 0; mi < 4; ++mi) {
        float rs[4] = {0.f, 0.f, 0.f, 0.f};
        #pragma unroll
        for (int ni = 0; ni < 4; ++ni) {
            const int gcol = bn * 128 + wn_ * 64 + ni * 16 + l15;
            const bool colv = (gcol < C_CLS);
            #pragma unroll
            for (int reg = 0; reg < 4; ++reg) {
                const int lrow = wm * 64 + mi * 16 + quad * 4 + reg;
                const float cosv = acc[mi][ni][reg] * invw[ni];
                const float sinv = sqrtf(fmaxf(1.0f - cosv * cosv, 0.0f));
                const float phi  = (cosv > TH_) ? (cosv * COSM - sinv * SINM) : (cosv - MM_);
                const bool ist   = colv && (gcol == ys[lrow]);
                const float logit = 64.0f * (ist ? phi : cosv);
                if (ist) atomicExch(&tlogit[bm * 128 + lrow], logit);
                rs[reg] += colv ? __expf(logit - 64.0f) : 0.0f;
            }
        }
        #pragma unroll
        for (int reg = 0; reg < 4; ++reg) {
            float v = rs[reg];
            v += __shfl_xor(v, 8, 64);
            v += __shfl_xor(v, 4, 64);
            v += __shfl_xor(v, 2, 64);
            v += __shfl_xor(v, 1, 64);
            if (l15 == 0) red[wn_][wm * 64 + mi * 16 + quad * 4 + reg] = v;
        }
    }
    __syncthreads();
    if (tid < 128) {
        const float v = red[0][tid] + red[1][tid];
        atomicAdd(&row_sum[bm * 128 + tid], v);
    }

    // ---- ticket: last block finalizes the loss ---------------------------
    __syncthreads();
    if (tid == 0) {
        const int t = atomicAdd(counter, 1);
        lastflag = (t == NBLK - 1) ? 1 : 0;
    }
    __syncthreads();
    if (lastflag) {
        float part = 0.0f;
        #pragma unroll
        for (int i = 0; i < 2; ++i) {
            const int row = tid + i * 256;
            const float rsv = atomicAdd(&row_sum[row], 0.0f);   // coherent read
            const float tlv = atomicAdd(&tlogit[row], 0.0f);    // coherent read
            part += logf(rsv) + 64.0f - tlv;
        }
        #pragma unroll
        for (int m = 32; m >= 1; m >>= 1) part += __shfl_xor(part, m, 64);
        if ((tid & 63) == 0) pr[tid >> 6] = part;
        __syncthreads();
        if (tid == 0)
            out[0] = (pr[0] + pr[1] + pr[2] + pr[3]) * (1.0f / 512.0f);
    }
}

extern "C" void kernel_launch(void* const* d_in, const int* in_sizes, int n_in,
                              void* d_out, int out_size, void* d_ws, size_t ws_size,
                              hipStream_t stream) {
    const float* x = (const float*)d_in[0];
    const int*   y = (const int*)d_in[1];
    const float* w = (const float*)d_in[2];

    char* ws = (char*)d_ws;
    __bf16* xn      = (__bf16*)ws;                     // 524288 B
    float*  row_sum = (float*)(ws + 524288);           // 2048 B
    float*  tlogit  = (float*)(ws + 524288 + 2048);    // 2048 B
    int*    counter = (int*)(ws + 524288 + 4096);      // 4 B
    float*  out     = (float*)d_out;

    hipLaunchKernelGGL(k_xnorm, dim3(128), dim3(256), 0, stream, x, xn, row_sum, counter);
    hipLaunchKernelGGL(k_gemm, dim3(NBLK), dim3(256), 0, stream,
                       xn, w, y, row_sum, tlogit, counter, out);
}

// Round 11
// 423.406 us; speedup vs baseline: 1.2231x; 1.0113x over previous
//
#include <hip/hip_runtime.h>
#include <hip/hip_bf16.h>
#include <cstdint>
#include <cstddef>

#define C_CLS   100000
#define D_FEAT  512
#define B_ROWS  512
#define NBN     782          /* ceil(100000/128) */
#define NBLK    (4 * NBN)    /* 3128 gemm blocks */
#define NORM_R4 ((C_CLS + B_ROWS) / 4)   /* 25128 row-groups of 4 */
#define NORM_GRID 2048

#define COSM 0.8775825618903728f
#define SINM 0.479425538604203f
#define TH_  (-0.8775825618903728f)
#define MM_  0.2397127693021015f   /* sin(0.5)*0.5 */

typedef __bf16 bf16x8 __attribute__((ext_vector_type(8)));
typedef float  f32x4  __attribute__((ext_vector_type(4)));

typedef __attribute__((address_space(3))) void lds_void;
typedef const __attribute__((address_space(1))) void g_void;

__device__ __forceinline__ void async_copy16(const void* g, void* l) {
    __builtin_amdgcn_global_load_lds((g_void*)g, (lds_void*)l, 16, 0, 0);
}

// ---------------- kernel 1: normalize ALL rows (w then x) -> bf16 ---------
// Grid-stride over 25128 row-groups (G11: 2048 blocks, ~12 groups each)
// instead of 25128 tiny blocks. Block 0 zeroes row_sum and the counter.
__global__ void k_norm(const float* __restrict__ x, const float* __restrict__ w,
                       __bf16* __restrict__ xn, __bf16* __restrict__ wn,
                       float* __restrict__ row_sum, int* __restrict__ counter) {
    if (blockIdx.x == 0) {
        row_sum[threadIdx.x]       = 0.0f;
        row_sum[threadIdx.x + 256] = 0.0f;
        if (threadIdx.x == 0) *counter = 0;
    }
    const int sub  = threadIdx.x >> 6;    // 0..3 row within group
    const int lane = threadIdx.x & 63;
    for (int g = blockIdx.x; g < NORM_R4; g += NORM_GRID) {
        const int r4 = g * 4 + sub;
        const float* src;
        __bf16*      dst;
        if (r4 < C_CLS) {
            src = w  + (size_t)r4 * D_FEAT;
            dst = wn + (size_t)r4 * D_FEAT;
        } else {
            src = x  + (size_t)(r4 - C_CLS) * D_FEAT;
            dst = xn + (size_t)(r4 - C_CLS) * D_FEAT;
        }
        const f32x4* p = (const f32x4*)src;
        f32x4 a = p[lane * 2];
        f32x4 b = p[lane * 2 + 1];
        float s = a[0]*a[0] + a[1]*a[1] + a[2]*a[2] + a[3]*a[3]
                + b[0]*b[0] + b[1]*b[1] + b[2]*b[2] + b[3]*b[3];
        #pragma unroll
        for (int m = 32; m >= 1; m >>= 1) s += __shfl_xor(s, m, 64);
        const float inv = 1.0f / fmaxf(sqrtf(s), 1e-12f);
        bf16x8 o;
        o[0] = (__bf16)(a[0]*inv); o[1] = (__bf16)(a[1]*inv);
        o[2] = (__bf16)(a[2]*inv); o[3] = (__bf16)(a[3]*inv);
        o[4] = (__bf16)(b[0]*inv); o[5] = (__bf16)(b[1]*inv);
        o[6] = (__bf16)(b[2]*inv); o[7] = (__bf16)(b[3]*inv);
        *(bf16x8*)(dst + lane * 8) = o;
    }
}

// ---------------- kernel 2: bf16 MFMA GEMM + fused finalization -----------
// The measured-best structure (round 7, 140 us): 16x16x32 MFMA, 128x128
// tile, 2 LDS buffers, counted vmcnt(4), two barriers per k-step,
// 3 blocks/CU. Epilogue: exp-sums atomicAdd into row_sum; tlogit via
// atomicExch; device-scope ticket -- last block computes the mean loss.
__global__ __launch_bounds__(256, 4) void k_gemm(
        const __bf16* __restrict__ xn, const __bf16* __restrict__ wn,
        const int* __restrict__ y,
        float* __restrict__ row_sum, float* __restrict__ tlogit,
        int* __restrict__ counter, float* __restrict__ out) {

    __shared__ __align__(16) __bf16 As[2][4096];   // [buf][quad*128+row][8] : 16 KB
    __shared__ __align__(16) __bf16 Bs[2][4096];   // [buf][quad*128+row][8] : 16 KB
    __shared__ int   ys[128];
    __shared__ float red[2][128];
    __shared__ int   lastflag;
    __shared__ float pr[4];

    const int tid = threadIdx.x;
    // XCD-aware swizzle: 3128 = 8*391 exact, XCD x gets [x*391, (x+1)*391)
    const int wg = (blockIdx.x & 7) * (NBLK / 8) + (blockIdx.x >> 3);
    const int bm = wg & 3;
    const int bn = wg >> 2;

    if (tid < 128) ys[tid] = y[bm * 128 + tid];

    const int wave = tid >> 6;
    const int lane = tid & 63;
    const int wm   = wave >> 1;     // 0..1
    const int wn_  = wave & 1;      // 0..1
    const int quad = lane >> 4;     // 0..3
    const int l15  = lane & 15;

    f32x4 acc[4][4];
    #pragma unroll
    for (int i = 0; i < 4; ++i)
        #pragma unroll
        for (int j = 0; j < 4; ++j) acc[i][j] = (f32x4){0.f, 0.f, 0.f, 0.f};

    // stage tile kt_ into buffer s: A and B each 512 x 16B chunks,
    // chunk c -> quad=c>>7, row=c&127. 4 global_load_lds / thread / tile.
    #define STAGE(s, kt_) do {                                                          \
        const int k0_ = (kt_) * 32;                                                     \
        _Pragma("unroll")                                                               \
        for (int i_ = 0; i_ < 2; ++i_) {                                                \
            const int c_ = tid + i_ * 256;                                              \
            const int qc_ = c_ >> 7, rc_ = c_ & 127;                                    \
            async_copy16(xn + (size_t)(bm * 128 + rc_) * D_FEAT + k0_ + qc_ * 8,        \
                         &As[s][c_ * 8]);                                               \
        }                                                                               \
        _Pragma("unroll")                                                               \
        for (int i_ = 0; i_ < 2; ++i_) {                                                \
            const int c_ = tid + i_ * 256;                                              \
            const int qc_ = c_ >> 7, rc_ = c_ & 127;                                    \
            int grow_ = bn * 128 + rc_; if (grow_ > C_CLS - 1) grow_ = C_CLS - 1;       \
            async_copy16(wn + (size_t)grow_ * D_FEAT + k0_ + qc_ * 8,                   \
                         &Bs[s][c_ * 8]);                                               \
        }                                                                               \
    } while (0)

    STAGE(0, 0);
    STAGE(1, 1);

    #pragma unroll
    for (int kt = 0; kt < 16; ++kt) {
        const int cur = kt & 1;

        // tile kt's 4 loads done; tile kt+1's 4 stay in flight
        if (kt < 15) asm volatile("s_waitcnt vmcnt(4)" ::: "memory");
        else         asm volatile("s_waitcnt vmcnt(0)" ::: "memory");
        __builtin_amdgcn_s_barrier();

        bf16x8 af[4];
        #pragma unroll
        for (int mi = 0; mi < 4; ++mi)
            af[mi] = *(const bf16x8*)&As[cur][(quad * 128 + wm * 64 + mi * 16 + l15) * 8];
        bf16x8 bfr[4];
        #pragma unroll
        for (int ni = 0; ni < 4; ++ni)
            bfr[ni] = *(const bf16x8*)&Bs[cur][(quad * 128 + wn_ * 64 + ni * 16 + l15) * 8];

        // all reads of buf[cur] retired -> safe to restage it
        asm volatile("s_waitcnt lgkmcnt(0)" ::: "memory");
        __builtin_amdgcn_s_barrier();
        if (kt < 14) STAGE(cur, kt + 2);

        #pragma unroll
        for (int mi = 0; mi < 4; ++mi)
            #pragma unroll
            for (int ni = 0; ni < 4; ++ni)
                acc[mi][ni] = __builtin_amdgcn_mfma_f32_16x16x32_bf16(af[mi], bfr[ni], acc[mi][ni], 0, 0, 0);
    }
    #undef STAGE

    // ---- epilogue: cos -> margin -> exp(logit-64) -> per-row partials ----
    #pragma unroll
    for (int mi = 0; mi < 4; ++mi) {
        float rs[4] = {0.f, 0.f, 0.f, 0.f};
        #pragma unroll
        for (int ni = 0; ni < 4; ++ni) {
            const int gcol = bn * 128 + wn_ * 64 + ni * 16 + l15;
            const bool colv = (gcol < C_CLS);
            #pragma unroll
            for (int reg = 0; reg < 4; ++reg) {
                const int lrow = wm * 64 + mi * 16 + quad * 4 + reg;
                const float cosv = acc[mi][ni][reg];
                const float sinv = sqrtf(fmaxf(1.0f - cosv * cosv, 0.0f));
                const float phi  = (cosv > TH_) ? (cosv * COSM - sinv * SINM) : (cosv - MM_);
                const bool ist   = colv && (gcol == ys[lrow]);
                const float logit = 64.0f * (ist ? phi : cosv);
                if (ist) atomicExch(&tlogit[bm * 128 + lrow], logit);
                rs[reg] += colv ? __expf(logit - 64.0f) : 0.0f;
            }
        }
        #pragma unroll
        for (int reg = 0; reg < 4; ++reg) {
            float v = rs[reg];
            v += __shfl_xor(v, 8, 64);
            v += __shfl_xor(v, 4, 64);
            v += __shfl_xor(v, 2, 64);
            v += __shfl_xor(v, 1, 64);
            if (l15 == 0) red[wn_][wm * 64 + mi * 16 + quad * 4 + reg] = v;
        }
    }
    __syncthreads();
    if (tid < 128) {
        const float v = red[0][tid] + red[1][tid];
        atomicAdd(&row_sum[bm * 128 + tid], v);
    }

    // ---- ticket: last block finalizes the loss ---------------------------
    __syncthreads();
    if (tid == 0) {
        const int t = atomicAdd(counter, 1);
        lastflag = (t == NBLK - 1) ? 1 : 0;
    }
    __syncthreads();
    if (lastflag) {
        float part = 0.0f;
        #pragma unroll
        for (int i = 0; i < 2; ++i) {
            const int row = tid + i * 256;
            const float rsv = atomicAdd(&row_sum[row], 0.0f);   // coherent read
            const float tlv = atomicAdd(&tlogit[row], 0.0f);    // coherent read
            part += logf(rsv) + 64.0f - tlv;
        }
        #pragma unroll
        for (int m = 32; m >= 1; m >>= 1) part += __shfl_xor(part, m, 64);
        if ((tid & 63) == 0) pr[tid >> 6] = part;
        __syncthreads();
        if (tid == 0)
            out[0] = (pr[0] + pr[1] + pr[2] + pr[3]) * (1.0f / 512.0f);
    }
}

extern "C" void kernel_launch(void* const* d_in, const int* in_sizes, int n_in,
                              void* d_out, int out_size, void* d_ws, size_t ws_size,
                              hipStream_t stream) {
    const float* x = (const float*)d_in[0];
    const int*   y = (const int*)d_in[1];
    const float* w = (const float*)d_in[2];

    char* ws = (char*)d_ws;
    __bf16* xn      = (__bf16*)ws;                                // 524288 B
    __bf16* wn      = (__bf16*)(ws + 524288);                     // 102400000 B
    float*  row_sum = (float*)(ws + 524288 + 102400000);          // 2048 B
    float*  tlogit  = (float*)(ws + 524288 + 102400000 + 2048);   // 2048 B
    int*    counter = (int*)(ws + 524288 + 102400000 + 4096);     // 4 B
    float*  out     = (float*)d_out;

    hipLaunchKernelGGL(k_norm, dim3(NORM_GRID), dim3(256), 0, stream,
                       x, w, xn, wn, row_sum, counter);
    hipLaunchKernelGGL(k_gemm, dim3(NBLK), dim3(256), 0, stream,
                       xn, wn, y, row_sum, tlogit, counter, out);
}

// Round 12
// 415.807 us; speedup vs baseline: 1.2455x; 1.0183x over previous
//
#include <hip/hip_runtime.h>
#include <hip/hip_bf16.h>
#include <cstdint>
#include <cstddef>

#define C_CLS   100000
#define D_FEAT  512
#define B_ROWS  512
#define NBN     782          /* ceil(100000/128) */
#define NBLK    (4 * NBN)    /* 3128 gemm blocks */

#define COSM 0.8775825618903728f
#define SINM 0.479425538604203f
#define TH_  (-0.8775825618903728f)
#define MM_  0.2397127693021015f   /* sin(0.5)*0.5 */

typedef __bf16 bf16x8 __attribute__((ext_vector_type(8)));
typedef float  f32x4  __attribute__((ext_vector_type(4)));

typedef __attribute__((address_space(3))) void lds_void;
typedef const __attribute__((address_space(1))) void g_void;

__device__ __forceinline__ void async_copy16(const void* g, void* l) {
    __builtin_amdgcn_global_load_lds((g_void*)g, (lds_void*)l, 16, 0, 0);
}

// ---------------- kernel 1: normalize ALL rows (w then x) -> bf16 ---------
// Round-7 exact form (best measured): blocks 0..24999 handle w rows
// (4/block); blocks 25000..25127 handle x rows. Block 25000 zeroes
// row_sum[512] and the ticket counter.
__global__ void k_norm(const float* __restrict__ x, const float* __restrict__ w,
                       __bf16* __restrict__ xn, __bf16* __restrict__ wn,
                       float* __restrict__ row_sum, int* __restrict__ counter) {
    const int r4   = blockIdx.x * 4 + (threadIdx.x >> 6);
    const int lane = threadIdx.x & 63;
    const float* src;
    __bf16*      dst;
    if (r4 < C_CLS) {
        src = w  + (size_t)r4 * D_FEAT;
        dst = wn + (size_t)r4 * D_FEAT;
    } else {
        src = x  + (size_t)(r4 - C_CLS) * D_FEAT;
        dst = xn + (size_t)(r4 - C_CLS) * D_FEAT;
    }
    const f32x4* p = (const f32x4*)src;
    f32x4 a = p[lane * 2];
    f32x4 b = p[lane * 2 + 1];
    float s = a[0]*a[0] + a[1]*a[1] + a[2]*a[2] + a[3]*a[3]
            + b[0]*b[0] + b[1]*b[1] + b[2]*b[2] + b[3]*b[3];
    #pragma unroll
    for (int m = 32; m >= 1; m >>= 1) s += __shfl_xor(s, m, 64);
    const float inv = 1.0f / fmaxf(sqrtf(s), 1e-12f);
    bf16x8 o;
    o[0] = (__bf16)(a[0]*inv); o[1] = (__bf16)(a[1]*inv);
    o[2] = (__bf16)(a[2]*inv); o[3] = (__bf16)(a[3]*inv);
    o[4] = (__bf16)(b[0]*inv); o[5] = (__bf16)(b[1]*inv);
    o[6] = (__bf16)(b[2]*inv); o[7] = (__bf16)(b[3]*inv);
    *(bf16x8*)(dst + lane * 8) = o;

    if (blockIdx.x == C_CLS / 4) {          // block 25000 (an x-block)
        row_sum[threadIdx.x]       = 0.0f;
        row_sum[threadIdx.x + 256] = 0.0f;
        if (threadIdx.x == 0) *counter = 0;
    }
}

// ---------------- kernel 2: bf16 MFMA GEMM + fused finalization -----------
// Measured-best structure (rounds 7/11, 140 us): 16x16x32 MFMA, 128x128
// tile, 2 LDS buffers, counted vmcnt(4), two barriers per k-step,
// 3 blocks/CU. Epilogue: exp-sums atomicAdd into row_sum; tlogit via
// atomicExch; device-scope ticket -- last block computes the mean loss.
// Eight alternative structures measured worse (rounds 3-6, 8-10).
__global__ __launch_bounds__(256, 4) void k_gemm(
        const __bf16* __restrict__ xn, const __bf16* __restrict__ wn,
        const int* __restrict__ y,
        float* __restrict__ row_sum, float* __restrict__ tlogit,
        int* __restrict__ counter, float* __restrict__ out) {

    __shared__ __align__(16) __bf16 As[2][4096];   // [buf][quad*128+row][8] : 16 KB
    __shared__ __align__(16) __bf16 Bs[2][4096];   // [buf][quad*128+row][8] : 16 KB
    __shared__ int   ys[128];
    __shared__ float red[2][128];
    __shared__ int   lastflag;
    __shared__ float pr[4];

    const int tid = threadIdx.x;
    // XCD-aware swizzle: 3128 = 8*391 exact, XCD x gets [x*391, (x+1)*391)
    const int wg = (blockIdx.x & 7) * (NBLK / 8) + (blockIdx.x >> 3);
    const int bm = wg & 3;
    const int bn = wg >> 2;

    if (tid < 128) ys[tid] = y[bm * 128 + tid];

    const int wave = tid >> 6;
    const int lane = tid & 63;
    const int wm   = wave >> 1;     // 0..1
    const int wn_  = wave & 1;      // 0..1
    const int quad = lane >> 4;     // 0..3
    const int l15  = lane & 15;

    f32x4 acc[4][4];
    #pragma unroll
    for (int i = 0; i < 4; ++i)
        #pragma unroll
        for (int j = 0; j < 4; ++j) acc[i][j] = (f32x4){0.f, 0.f, 0.f, 0.f};

    // stage tile kt_ into buffer s: A and B each 512 x 16B chunks,
    // chunk c -> quad=c>>7, row=c&127. 4 global_load_lds / thread / tile.
    #define STAGE(s, kt_) do {                                                          \
        const int k0_ = (kt_) * 32;                                                     \
        _Pragma("unroll")                                                               \
        for (int i_ = 0; i_ < 2; ++i_) {                                                \
            const int c_ = tid + i_ * 256;                                              \
            const int qc_ = c_ >> 7, rc_ = c_ & 127;                                    \
            async_copy16(xn + (size_t)(bm * 128 + rc_) * D_FEAT + k0_ + qc_ * 8,        \
                         &As[s][c_ * 8]);                                               \
        }                                                                               \
        _Pragma("unroll")                                                               \
        for (int i_ = 0; i_ < 2; ++i_) {                                                \
            const int c_ = tid + i_ * 256;                                              \
            const int qc_ = c_ >> 7, rc_ = c_ & 127;                                    \
            int grow_ = bn * 128 + rc_; if (grow_ > C_CLS - 1) grow_ = C_CLS - 1;       \
            async_copy16(wn + (size_t)grow_ * D_FEAT + k0_ + qc_ * 8,                   \
                         &Bs[s][c_ * 8]);                                               \
        }                                                                               \
    } while (0)

    STAGE(0, 0);
    STAGE(1, 1);

    #pragma unroll
    for (int kt = 0; kt < 16; ++kt) {
        const int cur = kt & 1;

        // tile kt's 4 loads done; tile kt+1's 4 stay in flight
        if (kt < 15) asm volatile("s_waitcnt vmcnt(4)" ::: "memory");
        else         asm volatile("s_waitcnt vmcnt(0)" ::: "memory");
        __builtin_amdgcn_s_barrier();

        bf16x8 af[4];
        #pragma unroll
        for (int mi = 0; mi < 4; ++mi)
            af[mi] = *(const bf16x8*)&As[cur][(quad * 128 + wm * 64 + mi * 16 + l15) * 8];
        bf16x8 bfr[4];
        #pragma unroll
        for (int ni = 0; ni < 4; ++ni)
            bfr[ni] = *(const bf16x8*)&Bs[cur][(quad * 128 + wn_ * 64 + ni * 16 + l15) * 8];

        // all reads of buf[cur] retired -> safe to restage it
        asm volatile("s_waitcnt lgkmcnt(0)" ::: "memory");
        __builtin_amdgcn_s_barrier();
        if (kt < 14) STAGE(cur, kt + 2);

        #pragma unroll
        for (int mi = 0; mi < 4; ++mi)
            #pragma unroll
            for (int ni = 0; ni < 4; ++ni)
                acc[mi][ni] = __builtin_amdgcn_mfma_f32_16x16x32_bf16(af[mi], bfr[ni], acc[mi][ni], 0, 0, 0);
    }
    #undef STAGE

    // ---- epilogue: cos -> margin -> exp(logit-64) -> per-row partials ----
    #pragma unroll
    for (int mi = 0; mi < 4; ++mi) {
        float rs[4] = {0.f, 0.f, 0.f, 0.f};
        #pragma unroll
        for (int ni = 0; ni < 4; ++ni) {
            const int gcol = bn * 128 + wn_ * 64 + ni * 16 + l15;
            const bool colv = (gcol < C_CLS);
            #pragma unroll
            for (int reg = 0; reg < 4; ++reg) {
                const int lrow = wm * 64 + mi * 16 + quad * 4 + reg;
                const float cosv = acc[mi][ni][reg];
                const float sinv = sqrtf(fmaxf(1.0f - cosv * cosv, 0.0f));
                const float phi  = (cosv > TH_) ? (cosv * COSM - sinv * SINM) : (cosv - MM_);
                const bool ist   = colv && (gcol == ys[lrow]);
                const float logit = 64.0f * (ist ? phi : cosv);
                if (ist) atomicExch(&tlogit[bm * 128 + lrow], logit);
                rs[reg] += colv ? __expf(logit - 64.0f) : 0.0f;
            }
        }
        #pragma unroll
        for (int reg = 0; reg < 4; ++reg) {
            float v = rs[reg];
            v += __shfl_xor(v, 8, 64);
            v += __shfl_xor(v, 4, 64);
            v += __shfl_xor(v, 2, 64);
            v += __shfl_xor(v, 1, 64);
            if (l15 == 0) red[wn_][wm * 64 + mi * 16 + quad * 4 + reg] = v;
        }
    }
    __syncthreads();
    if (tid < 128) {
        const float v = red[0][tid] + red[1][tid];
        atomicAdd(&row_sum[bm * 128 + tid], v);
    }

    // ---- ticket: last block finalizes the loss ---------------------------
    __syncthreads();
    if (tid == 0) {
        const int t = atomicAdd(counter, 1);
        lastflag = (t == NBLK - 1) ? 1 : 0;
    }
    __syncthreads();
    if (lastflag) {
        float part = 0.0f;
        #pragma unroll
        for (int i = 0; i < 2; ++i) {
            const int row = tid + i * 256;
            const float rsv = atomicAdd(&row_sum[row], 0.0f);   // coherent read
            const float tlv = atomicAdd(&tlogit[row], 0.0f);    // coherent read
            part += logf(rsv) + 64.0f - tlv;
        }
        #pragma unroll
        for (int m = 32; m >= 1; m >>= 1) part += __shfl_xor(part, m, 64);
        if ((tid & 63) == 0) pr[tid >> 6] = part;
        __syncthreads();
        if (tid == 0)
            out[0] = (pr[0] + pr[1] + pr[2] + pr[3]) * (1.0f / 512.0f);
    }
}

extern "C" void kernel_launch(void* const* d_in, const int* in_sizes, int n_in,
                              void* d_out, int out_size, void* d_ws, size_t ws_size,
                              hipStream_t stream) {
    const float* x = (const float*)d_in[0];
    const int*   y = (const int*)d_in[1];
    const float* w = (const float*)d_in[2];

    char* ws = (char*)d_ws;
    __bf16* xn      = (__bf16*)ws;                                // 524288 B
    __bf16* wn      = (__bf16*)(ws + 524288);                     // 102400000 B
    float*  row_sum = (float*)(ws + 524288 + 102400000);          // 2048 B
    float*  tlogit  = (float*)(ws + 524288 + 102400000 + 2048);   // 2048 B
    int*    counter = (int*)(ws + 524288 + 102400000 + 4096);     // 4 B
    float*  out     = (float*)d_out;

    hipLaunchKernelGGL(k_norm, dim3((C_CLS + B_ROWS) / 4), dim3(256), 0, stream,
                       x, w, xn, wn, row_sum, counter);
    hipLaunchKernelGGL(k_gemm, dim3(NBLK), dim3(256), 0, stream,
                       xn, wn, y, row_sum, tlogit, counter, out);
}